// Round 11
// baseline (1641.239 us; speedup 1.0000x reference)
//
#include <hip/hip_runtime.h>
#include <math.h>

#define S_LEN 1024
#define BATCH 64
#define EDIM  100
#define HDIM  128
#define G4    512
#define TAGS  17

typedef __attribute__((ext_vector_type(2))) float f32x2;
typedef __attribute__((ext_vector_type(4))) float f32x4;

__device__ __forceinline__ f32x2 pkfma(f32x2 a, f32x2 b, f32x2 c) {
    return __builtin_elementwise_fma(a, b, c);     // v_pk_fma_f32
}

// DPP quad-perm helpers (VALU, not DS pipe). xor1 = [1,0,3,2], xor2 = [2,3,0,1]
template<int CTRL>
__device__ __forceinline__ float qperm(float x) {
    int i = __float_as_int(x);
    i = __builtin_amdgcn_update_dpp(0, i, CTRL, 0xF, 0xF, true);
    return __int_as_float(i);
}
#define QX1 qperm<0xB1>
#define QX2 qperm<0x4E>

__device__ __forceinline__ float fast_tanh_u(float x) {   // 2*sigmoid(2x)-1
    float e = __expf(-2.f * x);
    return fmaf(2.f, __builtin_amdgcn_rcpf(1.f + e), -1.f);
}

// scalar broadcast of lane jj (VALU readlane, NO LDS round-trip)
#define RDLANE(v, jj) __int_as_float(__builtin_amdgcn_readlane(__float_as_int(v), (jj)))

// step barrier WITHOUT vmcnt drain: LDS ordered, global loads/stores stay in flight
#define STEP_BARRIER() do {                                          \
    __builtin_amdgcn_sched_barrier(0);                               \
    asm volatile("s_waitcnt lgkmcnt(0)\n\ts_barrier" ::: "memory");  \
    __builtin_amdgcn_sched_barrier(0);                               \
} while (0)

// ---------------------------------------------------------------------------
// Kernel 1: embed gather + input projection (byte-identical to round 10).
// ---------------------------------------------------------------------------
__global__ __launch_bounds__(256) void proj_kernel(
    const int* __restrict__ sentence, const float* __restrict__ embed,
    const float* __restrict__ w_ih_f, const float* __restrict__ b_ih_f, const float* __restrict__ b_hh_f,
    const float* __restrict__ w_ih_b, const float* __restrict__ b_ih_b, const float* __restrict__ b_hh_b,
    float* __restrict__ xg_f, float* __restrict__ xg_b, int t0)
{
    __shared__ __align__(16) float xf[16][EDIM];
    __shared__ __align__(16) float xb[16][EDIM];
    __shared__ int tok[32];
    const int tid  = threadIdx.x;
    const int row0 = blockIdx.x * 16;

    if (tid < 32) {
        int r = tid & 15;
        int row = row0 + r;
        int s = row >> 6, b = row & 63;
        int t = (tid < 16) ? (t0 + s) : (S_LEN - 1 - (t0 + s));
        tok[tid] = sentence[b * S_LEN + t];
    }
    __syncthreads();
    for (int i = tid; i < 16 * EDIM; i += 256) {
        int r = i / EDIM, e = i - r * EDIM;
        xf[r][e] = embed[(long)tok[r] * EDIM + e];
        xb[r][e] = embed[(long)tok[16 + r] * EDIM + e];
    }
    __syncthreads();

    const float* wptr[4];
    float bias[4];
#pragma unroll
    for (int ci = 0; ci < 4; ++ci) {
        int c = tid + 256 * ci;
        if (c < G4) { wptr[ci] = w_ih_f + c * EDIM; bias[ci] = b_ih_f[c] + b_hh_f[c]; }
        else { int cb = c - G4; wptr[ci] = w_ih_b + cb * EDIM; bias[ci] = b_ih_b[cb] + b_hh_b[cb]; }
    }

    float acc[4][16];
#pragma unroll
    for (int ci = 0; ci < 4; ++ci)
#pragma unroll
        for (int r = 0; r < 16; ++r) acc[ci][r] = 0.f;

    for (int e = 0; e < EDIM; e += 4) {
        float4 w4[4];
#pragma unroll
        for (int ci = 0; ci < 4; ++ci) w4[ci] = *(const float4*)(wptr[ci] + e);
#pragma unroll
        for (int r = 0; r < 16; ++r) {
            float4 xvf = *(const float4*)&xf[r][e];
            float4 xvb = *(const float4*)&xb[r][e];
#pragma unroll
            for (int ci = 0; ci < 4; ++ci) {
                float4 xv = (ci < 2) ? xvf : xvb;
                acc[ci][r] = fmaf(w4[ci].x, xv.x, acc[ci][r]);
                acc[ci][r] = fmaf(w4[ci].y, xv.y, acc[ci][r]);
                acc[ci][r] = fmaf(w4[ci].z, xv.z, acc[ci][r]);
                acc[ci][r] = fmaf(w4[ci].w, xv.w, acc[ci][r]);
            }
        }
    }

#pragma unroll
    for (int ci = 0; ci < 4; ++ci) {
        int c = tid + 256 * ci;
#pragma unroll
        for (int r = 0; r < 16; ++r) {
            int row = row0 + r;            // local (s*64 + b)
            float v = acc[ci][r] + bias[ci];
            if (c < G4) xg_f[(long)row * G4 + (c & 127) * 4 + (c >> 7)] = v;
            else { int cb = c - G4; xg_b[(long)row * G4 + (cb & 127) * 4 + (cb >> 7)] = v; }
        }
    }
}

// ---------------------------------------------------------------------------
// Kernel 2: LSTM scan. r9 compute structure, but ZERO per-step global stores:
// q==0 lanes write h into a 64-step LDS history ring (lgkm only); every 64
// steps all 512 threads flush the ring to hcat as coalesced dwordx4 bursts
// (reads -> barrier -> stores). In-order vmcnt queue analysis (r9/r10): the
// per-step hcat store made every xg-load wait retire a ~600cy HBM store;
// pollution now ~600cy per 64 steps (~+10cy/step).
// ---------------------------------------------------------------------------
__global__ __launch_bounds__(512, 1) void lstm_scan(
    const float* __restrict__ xg_f, const float* __restrict__ xg_b,
    const float* __restrict__ w_hh_f, const float* __restrict__ w_hh_b,
    float* __restrict__ hcat, float* __restrict__ h_state, float* __restrict__ c_state,
    int t0, int clen)
{
    const int t     = threadIdx.x;
    const int gid   = t >> 2, q = t & 3;
    const int b     = blockIdx.x & 63;
    const int dir   = blockIdx.x >> 6;
    const int chain = blockIdx.x;

    const float* whh = dir ? w_hh_b : w_hh_f;
    // weights: gate rows {g4*128+gid}, cols [32q, 32q+32), as packed pairs
    f32x2 wl[4][8], wh[4][8];
#pragma unroll
    for (int g4 = 0; g4 < 4; ++g4) {
        const f32x4* wr = (const f32x4*)(whh + (g4 * HDIM + gid) * HDIM + q * 32);
#pragma unroll
        for (int i = 0; i < 8; ++i) {
            f32x4 v = wr[i];
            wl[g4][i] = v.xy;
            wh[g4][i] = v.zw;
        }
    }

    __shared__ __align__(16) float h_lds[2][4][36];   // step exchange (padded)
    __shared__ __align__(16) float h_hist[64][HDIM];  // 64-step history ring, 32KB
    float c_reg = 0.f;
    if (t0 == 0) {
        if (t < HDIM) h_lds[0][t >> 5][t & 31] = 0.f;
    } else {
        c_reg = c_state[chain * HDIM + gid];
        if (t < HDIM) h_lds[0][t >> 5][t & 31] = h_state[chain * HDIM + t];
    }
    __syncthreads();

    const float* xgp = (dir ? xg_b : xg_f) + (long)b * G4 + gid * 4;
    float4 z4; z4.x = z4.y = z4.z = z4.w = 0.f;
    float4 xgc = *(const float4*)xgp;
    float4 xgn = (clen > 1) ? *(const float4*)(xgp + (long)BATCH * G4) : z4;

    float hv = 0.f;
    // flush-role constants: thread t covers (sl = t>>3, u0 = (t&7)*16)
    const int f_sl = t >> 3;
    const int f_u0 = (t & 7) * 16;
    float* hc_dir = hcat + dir * HDIM + f_u0;

    for (int s = 0; s < clen; ++s) {
        float4 xg2 = z4;
        if (s + 2 < clen) xg2 = *(const float4*)(xgp + (long)(s + 2) * BATCH * G4);

        const int cur = s & 1;
        const float* hp = &h_lds[cur][q][0];
        f32x2 ac0 = {0.f, 0.f}, ac1 = {0.f, 0.f}, ac2 = {0.f, 0.f}, ac3 = {0.f, 0.f};
#pragma unroll
        for (int i = 0; i < 8; ++i) {
            f32x4 h4 = *(const f32x4*)(hp + i * 4);
            f32x2 hlo = h4.xy, hhi = h4.zw;
            ac0 = pkfma(wl[0][i], hlo, ac0); ac0 = pkfma(wh[0][i], hhi, ac0);
            ac1 = pkfma(wl[1][i], hlo, ac1); ac1 = pkfma(wh[1][i], hhi, ac1);
            ac2 = pkfma(wl[2][i], hlo, ac2); ac2 = pkfma(wh[2][i], hhi, ac2);
            ac3 = pkfma(wl[3][i], hlo, ac3); ac3 = pkfma(wh[3][i], hhi, ac3);
        }
        float a0 = ac0.x + ac0.y, a1 = ac1.x + ac1.y;
        float a2 = ac2.x + ac2.y, a3 = ac3.x + ac3.y;

        // quad reduce: all lanes end with the full 128-wide sum per gate
        a0 += QX1(a0); a1 += QX1(a1); a2 += QX1(a2); a3 += QX1(a3);
        a0 += QX2(a0); a1 += QX2(a1); a2 += QX2(a2); a3 += QX2(a3);

        float av = (q == 0) ? a0 : (q == 1) ? a1 : (q == 2) ? a2 : a3;
        float xv = (q == 0) ? xgc.x : (q == 1) ? xgc.y : (q == 2) ? xgc.z : xgc.w;
        float pre = xv + av;                       // ref order: xg + dot
        float xin = (q == 2) ? 2.f * pre : pre;
        float e   = __expf(-xin);
        float sgm = __builtin_amdgcn_rcpf(1.f + e);
        float act = (q == 2) ? fmaf(2.f, sgm, -1.f) : sgm;
        float t1 = QX1(act);
        float t2 = QX2(act);
        float t3 = QX2(t1);
        float gi = (q == 0) ? act : (q == 1) ? t1 : (q == 2) ? t2 : t3;
        float gf = (q == 1) ? act : (q == 0) ? t1 : (q == 3) ? t2 : t3;
        float gg = (q == 2) ? act : (q == 3) ? t1 : (q == 0) ? t2 : t3;
        float go = (q == 3) ? act : (q == 2) ? t1 : (q == 1) ? t2 : t3;
        c_reg = gf * c_reg + gi * gg;              // sig(f)*c + sig(i)*tanh(g)
        hv = go * fast_tanh_u(c_reg);

        if (q == 0) {
            h_lds[cur ^ 1][gid >> 5][gid & 31] = hv;   // next-step exchange
            h_hist[s & 63][gid] = hv;                  // history ring (lgkm only)
        }
        STEP_BARRIER();
        xgc = xgn; xgn = xg2;

        if ((s & 63) == 63) {
            // flush ring window [s-63, s] -> hcat, coalesced.
            const int base_sl = s - 63;
            float4 v0 = *(const float4*)&h_hist[f_sl][f_u0 + 0];
            float4 v1 = *(const float4*)&h_hist[f_sl][f_u0 + 4];
            float4 v2 = *(const float4*)&h_hist[f_sl][f_u0 + 8];
            float4 v3 = *(const float4*)&h_hist[f_sl][f_u0 + 12];
            STEP_BARRIER();                        // reads drained before next writes
            int sg = t0 + base_sl + f_sl;
            int tg = dir ? (S_LEN - 1 - sg) : sg;
            float* dst = hc_dir + ((long)b * S_LEN + tg) * 256;
            *(float4*)(dst + 0)  = v0;
            *(float4*)(dst + 4)  = v1;
            *(float4*)(dst + 8)  = v2;
            *(float4*)(dst + 12) = v3;
        }
    }

    if (q == 0) {
        c_state[chain * HDIM + gid] = c_reg;
        h_state[chain * HDIM + gid] = hv;
    }
}

// ---------------------------------------------------------------------------
// Kernel 3: emissions (byte-identical to round 10).
// ---------------------------------------------------------------------------
__global__ __launch_bounds__(256) void fc_kernel(
    const float* __restrict__ hcat, const float* __restrict__ fc_w,
    const float* __restrict__ fc_b, float* __restrict__ em)
{
    __shared__ float w_lds[TAGS * 256];
    __shared__ float part[64 * TAGS * 4];
    const int tid = threadIdx.x;
    for (int i = tid; i < TAGS * 256; i += 256) w_lds[i] = fc_w[i];
    __syncthreads();

    const int r = tid >> 2, p = tid & 3;
    const long row = (long)blockIdx.x * 64 + r;
    const float* hrow = hcat + row * 256 + p * 64;

    float acc[TAGS];
#pragma unroll
    for (int tg = 0; tg < TAGS; ++tg) acc[tg] = 0.f;

    for (int e4 = 0; e4 < 16; ++e4) {
        float4 xv = *(const float4*)(hrow + e4 * 4);
        const float* wp = w_lds + p * 64 + e4 * 4;
#pragma unroll
        for (int tg = 0; tg < TAGS; ++tg) {
            acc[tg] = fmaf(xv.x, wp[tg * 256 + 0], acc[tg]);
            acc[tg] = fmaf(xv.y, wp[tg * 256 + 1], acc[tg]);
            acc[tg] = fmaf(xv.z, wp[tg * 256 + 2], acc[tg]);
            acc[tg] = fmaf(xv.w, wp[tg * 256 + 3], acc[tg]);
        }
    }
#pragma unroll
    for (int tg = 0; tg < TAGS; ++tg) part[(r * TAGS + tg) * 4 + p] = acc[tg];
    __syncthreads();

    for (int idx = tid; idx < 64 * TAGS; idx += 256) {
        int rr = idx / TAGS, tg = idx - rr * TAGS;
        const float* pp = part + (rr * TAGS + tg) * 4;
        float v = ((pp[0] + pp[1]) + (pp[2] + pp[3])) + fc_b[tg];
        em[((long)blockIdx.x * 64 + rr) * TAGS + tg] = v;
    }
}

// ---------------------------------------------------------------------------
// Kernel 4: Viterbi. r10 math, with the forward loop unrolled x2 so the
// scheduler can overlap argfirst(s) (off-path) with readlanes(s+1) — cross-
// iteration scheduling requires the back-edge removed.
// ---------------------------------------------------------------------------
#define MAX3(a,b,c) fmaxf(fmaxf((a),(b)),(c))
#define MIN3(a,b,c) min(min((a),(b)),(c))

__device__ __forceinline__ float max17(const float* a) {
    float m0 = MAX3(a[0], a[1], a[2]);
    float m1 = MAX3(a[3], a[4], a[5]);
    float m2 = MAX3(a[6], a[7], a[8]);
    float m3 = MAX3(a[9], a[10], a[11]);
    float m4 = MAX3(a[12], a[13], a[14]);
    float m5 = fmaxf(a[15], a[16]);
    float n0 = MAX3(m0, m1, m2);
    float n1 = MAX3(m3, m4, m5);
    return fmaxf(n0, n1);
}
__device__ __forceinline__ int argfirst17(const float* a, float em, float best) {
    int c[17];
#pragma unroll
    for (int j = 0; j < 17; ++j) c[j] = (a[j] + em == best) ? j : 255;
    int m0 = MIN3(c[0], c[1], c[2]);
    int m1 = MIN3(c[3], c[4], c[5]);
    int m2 = MIN3(c[6], c[7], c[8]);
    int m3 = MIN3(c[9], c[10], c[11]);
    int m4 = MIN3(c[12], c[13], c[14]);
    int m5 = min(c[15], c[16]);
    int n0 = MIN3(m0, m1, m2);
    int n1 = MIN3(m3, m4, m5);
    return min(n0, n1);
}

__global__ __launch_bounds__(64) void viterbi_kernel(
    const float* __restrict__ em,
    const float* __restrict__ start_trans, const float* __restrict__ end_trans,
    const float* __restrict__ trans, int* __restrict__ out)
{
    const int b = blockIdx.x;
    const int lane = threadIdx.x;
    __shared__ __align__(16) float e_lds[S_LEN * TAGS];      // 68 KB
    __shared__ unsigned char hist[(S_LEN - 1) * TAGS];
    __shared__ int tags[S_LEN];

    {
        const float4* ef4 = (const float4*)(em + (long)b * S_LEN * TAGS);
        float4* el4 = (float4*)e_lds;
        for (int i = lane; i < (S_LEN * TAGS) / 4; i += 64) el4[i] = ef4[i];
    }
    const int cl = (lane < TAGS) ? lane : 0;    // lanes >=17 shadow lane 0
    float tcol[TAGS], etr[TAGS];
#pragma unroll
    for (int jj = 0; jj < TAGS; ++jj) {
        tcol[jj] = trans[jj * TAGS + cl];
        etr[jj]  = end_trans[jj];
    }
    __syncthreads();

    float sc = start_trans[cl] + e_lds[cl];

    float em_cur = e_lds[1 * TAGS + cl];
#pragma unroll 2
    for (int s = 1; s < S_LEN; ++s) {
        int sn = (s + 1 < S_LEN) ? (s + 1) : s;
        float em_next = e_lds[sn * TAGS + cl];  // prefetch, off the chain

        float a[TAGS];
#pragma unroll
        for (int jj = 0; jj < TAGS; ++jj)
            a[jj] = RDLANE(sc, jj) + tcol[jj];   // a_j = score_j + trans[j][c]

        float amax = max17(a);                   // critical path: depth-3 max3 tree
        float best = amax + em_cur;              // == max_j fl(a_j + em_cur)
        sc = best;

        int bi = argfirst17(a, em_cur, best);    // off-path: first-max index
        if (lane < TAGS) hist[(s - 1) * TAGS + lane] = (unsigned char)bi;
        em_cur = em_next;
    }

    {
        float ev[TAGS];
#pragma unroll
        for (int jj = 0; jj < TAGS; ++jj) ev[jj] = RDLANE(sc, jj) + etr[jj];
        float bestv = max17(ev);
        int c[17];
#pragma unroll
        for (int j = 0; j < 17; ++j) c[j] = (ev[j] == bestv) ? j : 255;
        int m0 = MIN3(c[0], c[1], c[2]);
        int m1 = MIN3(c[3], c[4], c[5]);
        int m2 = MIN3(c[6], c[7], c[8]);
        int m3 = MIN3(c[9], c[10], c[11]);
        int m4 = MIN3(c[12], c[13], c[14]);
        int m5 = min(c[15], c[16]);
        int bt = min(MIN3(m0, m1, m2), MIN3(m3, m4, m5));

        __syncthreads();                         // hist writes visible
        if (lane == 0) {
            int tag = bt;
            tags[S_LEN - 1] = tag;
            for (int s = S_LEN - 2; s >= 0; --s) {
                tag = hist[s * TAGS + tag];
                tags[s] = tag;
            }
        }
    }
    __syncthreads();
    for (int t = lane; t < S_LEN; t += 64) out[b * S_LEN + t] = tags[t];
}

// ---------------------------------------------------------------------------
extern "C" void kernel_launch(void* const* d_in, const int* in_sizes, int n_in,
                              void* d_out, int out_size, void* d_ws, size_t ws_size,
                              hipStream_t stream) {
    const int*   sentence    = (const int*)d_in[0];
    // d_in[1] = mask (all true; where(mask,...) is identity)
    const float* embed       = (const float*)d_in[2];
    const float* w_ih_f      = (const float*)d_in[3];
    const float* w_hh_f      = (const float*)d_in[4];
    const float* b_ih_f      = (const float*)d_in[5];
    const float* b_hh_f      = (const float*)d_in[6];
    const float* w_ih_b      = (const float*)d_in[7];
    const float* w_hh_b      = (const float*)d_in[8];
    const float* b_ih_b      = (const float*)d_in[9];
    const float* b_hh_b      = (const float*)d_in[10];
    const float* fc_w        = (const float*)d_in[11];
    const float* fc_b        = (const float*)d_in[12];
    const float* start_trans = (const float*)d_in[13];
    const float* end_trans   = (const float*)d_in[14];
    const float* trans       = (const float*)d_in[15];
    int* out = (int*)d_out;

    // Workspace ladder: pick the largest chunk C that fits ws_size.
    const size_t hcat_e  = (size_t)S_LEN * BATCH * 256;   // 16.8M fl
    const size_t em_e    = (size_t)S_LEN * BATCH * TAGS;  // 1.1M fl
    const size_t st_e    = (size_t)128 * HDIM;            // 16K fl each
    static const int cands[] = {1024, 512, 256, 128, 64};
    int C = 64;
    for (int ci = 0; ci < 5; ++ci) {
        size_t need = ((size_t)2 * cands[ci] * BATCH * G4 + hcat_e + em_e + 2 * st_e) * 4;
        if (need <= ws_size) { C = cands[ci]; break; }
    }

    float* ws      = (float*)d_ws;
    float* xg_f    = ws;
    float* xg_b    = xg_f + (size_t)C * BATCH * G4;
    float* hcat    = xg_b + (size_t)C * BATCH * G4;
    float* em      = hcat + hcat_e;
    float* h_state = em + em_e;
    float* c_state = h_state + st_e;

    for (int t0 = 0; t0 < S_LEN; t0 += C) {
        proj_kernel<<<(C * BATCH) / 16, 256, 0, stream>>>(
            sentence, embed, w_ih_f, b_ih_f, b_hh_f, w_ih_b, b_ih_b, b_hh_b,
            xg_f, xg_b, t0);
        lstm_scan<<<2 * BATCH, 512, 0, stream>>>(
            xg_f, xg_b, w_hh_f, w_hh_b, hcat, h_state, c_state, t0, C);
    }
    fc_kernel<<<(S_LEN * BATCH) / 64, 256, 0, stream>>>(hcat, fc_w, fc_b, em);
    viterbi_kernel<<<BATCH, 64, 0, stream>>>(em, start_trans, end_trans, trans, out);
}

// Round 12
// 1387.236 us; speedup vs baseline: 1.1831x; 1.1831x over previous
//
#include <hip/hip_runtime.h>
#include <math.h>

#define S_LEN 1024
#define BATCH 64
#define EDIM  100
#define HDIM  128
#define G4    512
#define TAGS  17
#define SGRP  15   // s-values per hist block: 15*17=255 threads

typedef __attribute__((ext_vector_type(2))) float f32x2;
typedef __attribute__((ext_vector_type(4))) float f32x4;

__device__ __forceinline__ f32x2 pkfma(f32x2 a, f32x2 b, f32x2 c) {
    return __builtin_elementwise_fma(a, b, c);     // v_pk_fma_f32
}

// DPP quad-perm helpers (VALU, not DS pipe). xor1 = [1,0,3,2], xor2 = [2,3,0,1]
template<int CTRL>
__device__ __forceinline__ float qperm(float x) {
    int i = __float_as_int(x);
    i = __builtin_amdgcn_update_dpp(0, i, CTRL, 0xF, 0xF, true);
    return __int_as_float(i);
}
#define QX1 qperm<0xB1>
#define QX2 qperm<0x4E>

__device__ __forceinline__ float fast_tanh_u(float x) {   // 2*sigmoid(2x)-1
    float e = __expf(-2.f * x);
    return fmaf(2.f, __builtin_amdgcn_rcpf(1.f + e), -1.f);
}

// scalar broadcast of lane jj (VALU readlane, NO LDS round-trip)
#define RDLANE(v, jj) __int_as_float(__builtin_amdgcn_readlane(__float_as_int(v), (jj)))

// step barrier WITHOUT vmcnt drain: LDS ordered, global loads/stores stay in flight
#define STEP_BARRIER() do {                                          \
    __builtin_amdgcn_sched_barrier(0);                               \
    asm volatile("s_waitcnt lgkmcnt(0)\n\ts_barrier" ::: "memory");  \
    __builtin_amdgcn_sched_barrier(0);                               \
} while (0)

// ---------------------------------------------------------------------------
// Kernel 1: embed gather + input projection (byte-identical to round 10).
// ---------------------------------------------------------------------------
__global__ __launch_bounds__(256) void proj_kernel(
    const int* __restrict__ sentence, const float* __restrict__ embed,
    const float* __restrict__ w_ih_f, const float* __restrict__ b_ih_f, const float* __restrict__ b_hh_f,
    const float* __restrict__ w_ih_b, const float* __restrict__ b_ih_b, const float* __restrict__ b_hh_b,
    float* __restrict__ xg_f, float* __restrict__ xg_b, int t0)
{
    __shared__ __align__(16) float xf[16][EDIM];
    __shared__ __align__(16) float xb[16][EDIM];
    __shared__ int tok[32];
    const int tid  = threadIdx.x;
    const int row0 = blockIdx.x * 16;

    if (tid < 32) {
        int r = tid & 15;
        int row = row0 + r;
        int s = row >> 6, b = row & 63;
        int t = (tid < 16) ? (t0 + s) : (S_LEN - 1 - (t0 + s));
        tok[tid] = sentence[b * S_LEN + t];
    }
    __syncthreads();
    for (int i = tid; i < 16 * EDIM; i += 256) {
        int r = i / EDIM, e = i - r * EDIM;
        xf[r][e] = embed[(long)tok[r] * EDIM + e];
        xb[r][e] = embed[(long)tok[16 + r] * EDIM + e];
    }
    __syncthreads();

    const float* wptr[4];
    float bias[4];
#pragma unroll
    for (int ci = 0; ci < 4; ++ci) {
        int c = tid + 256 * ci;
        if (c < G4) { wptr[ci] = w_ih_f + c * EDIM; bias[ci] = b_ih_f[c] + b_hh_f[c]; }
        else { int cb = c - G4; wptr[ci] = w_ih_b + cb * EDIM; bias[ci] = b_ih_b[cb] + b_hh_b[cb]; }
    }

    float acc[4][16];
#pragma unroll
    for (int ci = 0; ci < 4; ++ci)
#pragma unroll
        for (int r = 0; r < 16; ++r) acc[ci][r] = 0.f;

    for (int e = 0; e < EDIM; e += 4) {
        float4 w4[4];
#pragma unroll
        for (int ci = 0; ci < 4; ++ci) w4[ci] = *(const float4*)(wptr[ci] + e);
#pragma unroll
        for (int r = 0; r < 16; ++r) {
            float4 xvf = *(const float4*)&xf[r][e];
            float4 xvb = *(const float4*)&xb[r][e];
#pragma unroll
            for (int ci = 0; ci < 4; ++ci) {
                float4 xv = (ci < 2) ? xvf : xvb;
                acc[ci][r] = fmaf(w4[ci].x, xv.x, acc[ci][r]);
                acc[ci][r] = fmaf(w4[ci].y, xv.y, acc[ci][r]);
                acc[ci][r] = fmaf(w4[ci].z, xv.z, acc[ci][r]);
                acc[ci][r] = fmaf(w4[ci].w, xv.w, acc[ci][r]);
            }
        }
    }

#pragma unroll
    for (int ci = 0; ci < 4; ++ci) {
        int c = tid + 256 * ci;
#pragma unroll
        for (int r = 0; r < 16; ++r) {
            int row = row0 + r;            // local (s*64 + b)
            float v = acc[ci][r] + bias[ci];
            if (c < G4) xg_f[(long)row * G4 + (c & 127) * 4 + (c >> 7)] = v;
            else { int cb = c - G4; xg_b[(long)row * G4 + (cb & 127) * 4 + (cb >> 7)] = v; }
        }
    }
}

// ---------------------------------------------------------------------------
// Kernel 2: LSTM scan — byte-identical to round 10 (best measured: 350 us).
// r11's LDS-ring variant regressed (+63 us, +393K bank conflicts) — reverted.
// ---------------------------------------------------------------------------
__global__ __launch_bounds__(512, 1) void lstm_scan(
    const float* __restrict__ xg_f, const float* __restrict__ xg_b,
    const float* __restrict__ w_hh_f, const float* __restrict__ w_hh_b,
    float* __restrict__ hcat, float* __restrict__ h_state, float* __restrict__ c_state,
    int t0, int clen)
{
    const int t     = threadIdx.x;
    const int gid   = t >> 2, q = t & 3;
    const int b     = blockIdx.x & 63;
    const int dir   = blockIdx.x >> 6;
    const int chain = blockIdx.x;

    const float* whh = dir ? w_hh_b : w_hh_f;
    f32x2 wl[4][8], wh[4][8];
#pragma unroll
    for (int g4 = 0; g4 < 4; ++g4) {
        const f32x4* wr = (const f32x4*)(whh + (g4 * HDIM + gid) * HDIM + q * 32);
#pragma unroll
        for (int i = 0; i < 8; ++i) {
            f32x4 v = wr[i];
            wl[g4][i] = v.xy;
            wh[g4][i] = v.zw;
        }
    }

    __shared__ __align__(16) float h_lds[2][4][36];
    float c_reg = 0.f;
    if (t0 == 0) {
        if (t < HDIM) h_lds[0][t >> 5][t & 31] = 0.f;
    } else {
        c_reg = c_state[chain * HDIM + gid];
        if (t < HDIM) h_lds[0][t >> 5][t & 31] = h_state[chain * HDIM + t];
    }
    __syncthreads();

    const float* xgp = (dir ? xg_b : xg_f) + (long)b * G4 + gid * 4;
    float4 z4; z4.x = z4.y = z4.z = z4.w = 0.f;
    float4 xgc = *(const float4*)xgp;
    float4 xgn = (clen > 1) ? *(const float4*)(xgp + (long)BATCH * G4) : z4;

    float* hc_base = hcat + (long)b * S_LEN * 256 + dir * HDIM + gid;
    float hv = 0.f;
    float hbuf[8];

    for (int sb = 0; sb < clen; sb += 8) {
#pragma unroll
        for (int k = 0; k < 8; ++k) {
            const int s = sb + k;
            float4 xg2 = z4;
            if (s + 2 < clen) xg2 = *(const float4*)(xgp + (long)(s + 2) * BATCH * G4);

            const int cur = k & 1;
            const float* hp = &h_lds[cur][q][0];
            f32x2 ac0 = {0.f, 0.f}, ac1 = {0.f, 0.f}, ac2 = {0.f, 0.f}, ac3 = {0.f, 0.f};
#pragma unroll
            for (int i = 0; i < 8; ++i) {
                f32x4 h4 = *(const f32x4*)(hp + i * 4);
                f32x2 hlo = h4.xy, hhi = h4.zw;
                ac0 = pkfma(wl[0][i], hlo, ac0); ac0 = pkfma(wh[0][i], hhi, ac0);
                ac1 = pkfma(wl[1][i], hlo, ac1); ac1 = pkfma(wh[1][i], hhi, ac1);
                ac2 = pkfma(wl[2][i], hlo, ac2); ac2 = pkfma(wh[2][i], hhi, ac2);
                ac3 = pkfma(wl[3][i], hlo, ac3); ac3 = pkfma(wh[3][i], hhi, ac3);
            }
            float a0 = ac0.x + ac0.y, a1 = ac1.x + ac1.y;
            float a2 = ac2.x + ac2.y, a3 = ac3.x + ac3.y;

            a0 += QX1(a0); a1 += QX1(a1); a2 += QX1(a2); a3 += QX1(a3);
            a0 += QX2(a0); a1 += QX2(a1); a2 += QX2(a2); a3 += QX2(a3);

            float av = (q == 0) ? a0 : (q == 1) ? a1 : (q == 2) ? a2 : a3;
            float xv = (q == 0) ? xgc.x : (q == 1) ? xgc.y : (q == 2) ? xgc.z : xgc.w;
            float pre = xv + av;                   // ref order: xg + dot
            float xin = (q == 2) ? 2.f * pre : pre;
            float e   = __expf(-xin);
            float sgm = __builtin_amdgcn_rcpf(1.f + e);
            float act = (q == 2) ? fmaf(2.f, sgm, -1.f) : sgm;
            float t1 = QX1(act);
            float t2 = QX2(act);
            float t3 = QX2(t1);
            float gi = (q == 0) ? act : (q == 1) ? t1 : (q == 2) ? t2 : t3;
            float gf = (q == 1) ? act : (q == 0) ? t1 : (q == 3) ? t2 : t3;
            float gg = (q == 2) ? act : (q == 3) ? t1 : (q == 0) ? t2 : t3;
            float go = (q == 3) ? act : (q == 2) ? t1 : (q == 1) ? t2 : t3;
            c_reg = gf * c_reg + gi * gg;          // sig(f)*c + sig(i)*tanh(g)
            hv = go * fast_tanh_u(c_reg);
            hbuf[k] = hv;

            if (q == 0) h_lds[cur ^ 1][gid >> 5][gid & 31] = hv;
            STEP_BARRIER();
            xgc = xgn; xgn = xg2;
        }
        if (q == 0) {
#pragma unroll
            for (int k = 0; k < 8; ++k) {
                int tg = dir ? (S_LEN - 1 - (t0 + sb + k)) : (t0 + sb + k);
                hc_base[(long)tg * 256] = hbuf[k];
            }
        }
    }

    if (q == 0) {
        c_state[chain * HDIM + gid] = c_reg;
        h_state[chain * HDIM + gid] = hv;
    }
}

// ---------------------------------------------------------------------------
// Kernel 3: emissions (byte-identical to round 10).
// ---------------------------------------------------------------------------
__global__ __launch_bounds__(256) void fc_kernel(
    const float* __restrict__ hcat, const float* __restrict__ fc_w,
    const float* __restrict__ fc_b, float* __restrict__ em)
{
    __shared__ float w_lds[TAGS * 256];
    __shared__ float part[64 * TAGS * 4];
    const int tid = threadIdx.x;
    for (int i = tid; i < TAGS * 256; i += 256) w_lds[i] = fc_w[i];
    __syncthreads();

    const int r = tid >> 2, p = tid & 3;
    const long row = (long)blockIdx.x * 64 + r;
    const float* hrow = hcat + row * 256 + p * 64;

    float acc[TAGS];
#pragma unroll
    for (int tg = 0; tg < TAGS; ++tg) acc[tg] = 0.f;

    for (int e4 = 0; e4 < 16; ++e4) {
        float4 xv = *(const float4*)(hrow + e4 * 4);
        const float* wp = w_lds + p * 64 + e4 * 4;
#pragma unroll
        for (int tg = 0; tg < TAGS; ++tg) {
            acc[tg] = fmaf(xv.x, wp[tg * 256 + 0], acc[tg]);
            acc[tg] = fmaf(xv.y, wp[tg * 256 + 1], acc[tg]);
            acc[tg] = fmaf(xv.z, wp[tg * 256 + 2], acc[tg]);
            acc[tg] = fmaf(xv.w, wp[tg * 256 + 3], acc[tg]);
        }
    }
#pragma unroll
    for (int tg = 0; tg < TAGS; ++tg) part[(r * TAGS + tg) * 4 + p] = acc[tg];
    __syncthreads();

    for (int idx = tid; idx < 64 * TAGS; idx += 256) {
        int rr = idx / TAGS, tg = idx - rr * TAGS;
        const float* pp = part + (rr * TAGS + tg) * 4;
        float v = ((pp[0] + pp[1]) + (pp[2] + pp[3])) + fc_b[tg];
        em[((long)blockIdx.x * 64 + rr) * TAGS + tg] = v;
    }
}

// ---------------------------------------------------------------------------
// Kernel 4A: Viterbi score pass — VALUES ONLY. Per-step: 17 readlane + 17 add
// + depth-3 max3 tree + 1 add (~50 instr, no argfirst). Score vector stored
// to global each step (no vmcnt waits exist in the loop: em is LDS-staged,
// so stores retire fully off the critical path). Values bit-identical to r10.
// ---------------------------------------------------------------------------
#define MAX3(a,b,c) fmaxf(fmaxf((a),(b)),(c))
#define MIN3(a,b,c) min(min((a),(b)),(c))

__device__ __forceinline__ float max17(const float* a) {
    float m0 = MAX3(a[0], a[1], a[2]);
    float m1 = MAX3(a[3], a[4], a[5]);
    float m2 = MAX3(a[6], a[7], a[8]);
    float m3 = MAX3(a[9], a[10], a[11]);
    float m4 = MAX3(a[12], a[13], a[14]);
    float m5 = fmaxf(a[15], a[16]);
    float n0 = MAX3(m0, m1, m2);
    float n1 = MAX3(m3, m4, m5);
    return fmaxf(n0, n1);
}

__global__ __launch_bounds__(64) void viterbi_score(
    const float* __restrict__ em,
    const float* __restrict__ start_trans, const float* __restrict__ end_trans,
    const float* __restrict__ trans,
    float* __restrict__ scores, int* __restrict__ last_tag)
{
    const int b = blockIdx.x;
    const int lane = threadIdx.x;
    __shared__ __align__(16) float e_lds[S_LEN * TAGS];      // 68 KB

    {
        const float4* ef4 = (const float4*)(em + (long)b * S_LEN * TAGS);
        float4* el4 = (float4*)e_lds;
        for (int i = lane; i < (S_LEN * TAGS) / 4; i += 64) el4[i] = ef4[i];
    }
    const int cl = (lane < TAGS) ? lane : 0;    // lanes >=17 shadow lane 0
    float tcol[TAGS], etr[TAGS];
#pragma unroll
    for (int jj = 0; jj < TAGS; ++jj) {
        tcol[jj] = trans[jj * TAGS + cl];
        etr[jj]  = end_trans[jj];
    }
    __syncthreads();

    float sc = start_trans[cl] + e_lds[cl];
    float* sb = scores + (long)b * S_LEN * TAGS + cl;
    if (lane < TAGS) sb[0] = sc;                 // score_0

    float em_cur = e_lds[1 * TAGS + cl];
#pragma unroll 2
    for (int s = 1; s < S_LEN; ++s) {
        int sn = (s + 1 < S_LEN) ? (s + 1) : s;
        float em_next = e_lds[sn * TAGS + cl];   // prefetch, off the chain

        float a[TAGS];
#pragma unroll
        for (int jj = 0; jj < TAGS; ++jj)
            a[jj] = RDLANE(sc, jj) + tcol[jj];

        float amax = max17(a);                   // depth-3 max3 tree
        sc = amax + em_cur;                      // == max_j fl(a_j + em_cur)
        if (lane < TAGS) sb[(long)s * TAGS] = sc;  // score_s (store, never waited on)
        em_cur = em_next;
    }

    // final argmax over score + end_trans (first-max)
    {
        float ev[TAGS];
#pragma unroll
        for (int jj = 0; jj < TAGS; ++jj) ev[jj] = RDLANE(sc, jj) + etr[jj];
        float bestv = max17(ev);
        int c[17];
#pragma unroll
        for (int j = 0; j < 17; ++j) c[j] = (ev[j] == bestv) ? j : 255;
        int m0 = MIN3(c[0], c[1], c[2]);
        int m1 = MIN3(c[3], c[4], c[5]);
        int m2 = MIN3(c[6], c[7], c[8]);
        int m3 = MIN3(c[9], c[10], c[11]);
        int m4 = MIN3(c[12], c[13], c[14]);
        int m5 = min(c[15], c[16]);
        int bt = min(MIN3(m0, m1, m2), MIN3(m3, m4, m5));
        if (lane == 0) last_tag[b] = bt;
    }
}

// ---------------------------------------------------------------------------
// Kernel 4B: hist pass — massively parallel. hist[b][s][c] = smallest j with
// fl(fl(score_{s-1}[j] + trans[j][c]) + em_s[c]) == score_s[c]. Exactly r10's
// argfirst formula; all operands LDS-staged.
// ---------------------------------------------------------------------------
__global__ __launch_bounds__(256) void hist_kernel(
    const float* __restrict__ scores, const float* __restrict__ em,
    const float* __restrict__ trans, unsigned char* __restrict__ hist_g)
{
    const int nb = (S_LEN - 1 + SGRP - 1) / SGRP;   // 69 groups per batch
    const int b = blockIdx.x / nb, g = blockIdx.x % nb;
    const int t = threadIdx.x;
    __shared__ float s_sc[(SGRP + 1) * TAGS];       // rows g*15 .. g*15+15
    __shared__ float s_em[(SGRP + 1) * TAGS];
    __shared__ float s_tr[TAGS * TAGS];

    const long b_base = (long)b * S_LEN * TAGS;
    const long maxoff = (long)S_LEN * TAGS - 1;
    for (int i = t; i < (SGRP + 1) * TAGS; i += 256) {
        long off = (long)g * SGRP * TAGS + i;
        long co  = off > maxoff ? maxoff : off;     // clamp at sequence end
        s_sc[i] = scores[b_base + co];
        s_em[i] = em[b_base + co];
    }
    for (int i = t; i < TAGS * TAGS; i += 256) s_tr[i] = trans[i];
    __syncthreads();

    if (t >= SGRP * TAGS) return;
    const int sl = t / TAGS, c = t - sl * TAGS;
    const int s = g * SGRP + sl + 1;
    if (s >= S_LEN) return;

    const float* sprev = s_sc + sl * TAGS;          // score_{s-1}
    const float emv = s_em[(sl + 1) * TAGS + c];    // em_s[c]
    const float cur = s_sc[(sl + 1) * TAGS + c];    // score_s[c]

    int bi = 255;
#pragma unroll
    for (int j = TAGS - 1; j >= 0; --j) {           // descending: smallest j wins
        float v = (sprev[j] + s_tr[j * TAGS + c]) + emv;
        if (v == cur) bi = j;
    }
    hist_g[((long)b * S_LEN + s) * TAGS + c] = (unsigned char)bi;
}

// ---------------------------------------------------------------------------
// Kernel 4C: backtrace — stage hist[b] (17.4 KB) into LDS coalesced, walk it.
// ---------------------------------------------------------------------------
__global__ __launch_bounds__(64) void backtrace_kernel(
    const unsigned char* __restrict__ hist_g, const int* __restrict__ last_tag,
    int* __restrict__ out)
{
    const int b = blockIdx.x;
    const int lane = threadIdx.x;
    __shared__ int hist_i[(S_LEN * TAGS) / 4];      // 17408 B
    __shared__ int tags[S_LEN];

    const int* hg = (const int*)(hist_g + (long)b * S_LEN * TAGS);  // 17408 B/b, 4-aligned
    for (int i = lane; i < (S_LEN * TAGS) / 4; i += 64) hist_i[i] = hg[i];
    __syncthreads();

    if (lane == 0) {
        const unsigned char* hl = (const unsigned char*)hist_i;
        int tag = last_tag[b];
        tags[S_LEN - 1] = tag;
        for (int s = S_LEN - 2; s >= 0; --s) {
            tag = hl[(s + 1) * TAGS + tag];
            tags[s] = tag;
        }
    }
    __syncthreads();
    for (int t = lane; t < S_LEN; t += 64) out[b * S_LEN + t] = tags[t];
}

// ---------------------------------------------------------------------------
extern "C" void kernel_launch(void* const* d_in, const int* in_sizes, int n_in,
                              void* d_out, int out_size, void* d_ws, size_t ws_size,
                              hipStream_t stream) {
    const int*   sentence    = (const int*)d_in[0];
    // d_in[1] = mask (all true; where(mask,...) is identity)
    const float* embed       = (const float*)d_in[2];
    const float* w_ih_f      = (const float*)d_in[3];
    const float* w_hh_f      = (const float*)d_in[4];
    const float* b_ih_f      = (const float*)d_in[5];
    const float* b_hh_f      = (const float*)d_in[6];
    const float* w_ih_b      = (const float*)d_in[7];
    const float* w_hh_b      = (const float*)d_in[8];
    const float* b_ih_b      = (const float*)d_in[9];
    const float* b_hh_b      = (const float*)d_in[10];
    const float* fc_w        = (const float*)d_in[11];
    const float* fc_b        = (const float*)d_in[12];
    const float* start_trans = (const float*)d_in[13];
    const float* end_trans   = (const float*)d_in[14];
    const float* trans       = (const float*)d_in[15];
    int* out = (int*)d_out;

    // Workspace ladder: pick the largest chunk C that fits ws_size.
    const size_t hcat_e = (size_t)S_LEN * BATCH * 256;    // 16.8M fl
    const size_t em_e   = (size_t)S_LEN * BATCH * TAGS;   // 1,114,112 fl
    const size_t st_e   = (size_t)128 * HDIM;             // 16K fl each
    const size_t hist_e = (em_e + 3) / 4;                 // floats holding em_e BYTES
    const size_t fixed  = hcat_e + 2 * em_e + 2 * st_e + hist_e + 64;
    static const int cands[] = {1024, 512, 256, 128, 64};
    int C = 64;
    for (int ci = 0; ci < 5; ++ci) {
        size_t need = ((size_t)2 * cands[ci] * BATCH * G4 + fixed) * 4;
        if (need <= ws_size) { C = cands[ci]; break; }
    }

    float* ws       = (float*)d_ws;
    float* xg_f     = ws;
    float* xg_b     = xg_f + (size_t)C * BATCH * G4;
    float* hcat     = xg_b + (size_t)C * BATCH * G4;
    float* em       = hcat + hcat_e;
    float* h_state  = em + em_e;
    float* c_state  = h_state + st_e;
    float* scores   = c_state + st_e;
    unsigned char* hist_g = (unsigned char*)(scores + em_e);
    int*   last_tag = (int*)(scores + em_e + hist_e);

    for (int t0 = 0; t0 < S_LEN; t0 += C) {
        proj_kernel<<<(C * BATCH) / 16, 256, 0, stream>>>(
            sentence, embed, w_ih_f, b_ih_f, b_hh_f, w_ih_b, b_ih_b, b_hh_b,
            xg_f, xg_b, t0);
        lstm_scan<<<2 * BATCH, 512, 0, stream>>>(
            xg_f, xg_b, w_hh_f, w_hh_b, hcat, h_state, c_state, t0, C);
    }
    fc_kernel<<<(S_LEN * BATCH) / 64, 256, 0, stream>>>(hcat, fc_w, fc_b, em);
    viterbi_score<<<BATCH, 64, 0, stream>>>(
        em, start_trans, end_trans, trans, scores, last_tag);
    const int nb = (S_LEN - 1 + SGRP - 1) / SGRP;   // 69
    hist_kernel<<<BATCH * nb, 256, 0, stream>>>(scores, em, trans, hist_g);
    backtrace_kernel<<<BATCH, 64, 0, stream>>>(hist_g, last_tag, out);
}